// Round 9
// baseline (181.438 us; speedup 1.0000x reference)
//
#include <hip/hip_runtime.h>
#include <cmath>

typedef __attribute__((ext_vector_type(8))) short short8;
typedef __attribute__((ext_vector_type(4))) float f32x4;

static __device__ __forceinline__ unsigned cvtpk(float lo, float hi) {
    unsigned r;
    asm("v_cvt_pk_bf16_f32 %0, %1, %2" : "=v"(r) : "v"(lo), "v"(hi));
    return r;
}
// 3-level RNE split of a pair of floats -> 3 packed-bf16 dwords; v = s1+s2+s3 + O(2^-27 |v|)
static __device__ __forceinline__ void split3pk(float v0, float v1,
                                                unsigned& o1, unsigned& o2, unsigned& o3) {
    o1 = cvtpk(v0, v1);
    float r0 = v0 - __uint_as_float(o1 << 16);
    float r1 = v1 - __uint_as_float(o1 & 0xffff0000u);
    o2 = cvtpk(r0, r1);
    float q0 = r0 - __uint_as_float(o2 << 16);
    float q1 = r1 - __uint_as_float(o2 & 0xffff0000u);
    o3 = cvtpk(q0, q1);
}

union FragU { short8 s; unsigned u[4]; };

#define PH 1048576   // h plane elems (16384*64)
#define PB 131072    // emb/W plane elems (2048*64)

// ---------------- prep: zero wacc + inv-norms + excitability bonus ----------
// global order: [qk 0..511][fv 512..767][q 768..1279][k(rel) 1280..1791][val 1792..2047]
__global__ void prep_kernel(const float* __restrict__ emb,
                            const float* __restrict__ emb_rel_k,
                            const float* __restrict__ ema_qk,
                            const float* __restrict__ ema_v,
                            const float* __restrict__ ema_rel,
                            const float* __restrict__ ema_val,
                            float* __restrict__ invn,
                            float* __restrict__ bonus,
                            float* __restrict__ wacc)
{
    int n = blockIdx.x * 64 + threadIdx.x;   // 32 x 64 -> 2048
    {
        float4 z = {0.f, 0.f, 0.f, 0.f};
        *(float4*)(wacc + (size_t)n * 8)     = z;
        *(float4*)(wacc + (size_t)n * 8 + 4) = z;
    }
    const float* row;
    float ema;
    if (n < 512)       { row = emb + (size_t)n * 64;                ema = ema_qk[n]; }
    else if (n < 768)  { row = emb + (size_t)n * 64;                ema = ema_v[n - 512]; }
    else if (n < 1280) { row = emb + (size_t)n * 64;                ema = ema_rel[n - 768]; }
    else if (n < 1792) { row = emb_rel_k + (size_t)(n - 1280) * 64; ema = ema_rel[n - 1280]; }
    else               { row = emb + (size_t)(n - 512) * 64;        ema = ema_val[n - 1792]; }
    float s = 0.f;
    #pragma unroll
    for (int k = 0; k < 64; k += 4) {
        float4 v = *(const float4*)(row + k);
        s += v.x*v.x + v.y*v.y + v.z*v.z + v.w*v.w;
    }
    invn[n] = 1.0f / sqrtf(s);
    float ex = 1.0f - ema * (1.0f / 1.5f);   // TAU = 1.5
    ex = fminf(fmaxf(ex, 0.f), 1.f);
    bonus[n] = ex * 1.0f;                    // EXC_W = 1.0
}

// ---------------- pack W into 3 bf16 split planes, MFMA B-fragment order ----
// plane: [ksg 0..63][t 0..3][lane 0..63][j 0..7]; col=16t+(l&15), k=ksg*32+(l>>4)*8+j
__global__ void wtpack3_kernel(const float* __restrict__ proj_w, unsigned short* __restrict__ wp)
{
    int idx = blockIdx.x * 256 + threadIdx.x;   // 16384
    int l = idx & 63;
    int t = (idx >> 6) & 3;
    int ksg = idx >> 8;
    int col = t * 16 + (l & 15);
    int kb = ksg * 32 + (l >> 4) * 8;
    float4 w0 = *(const float4*)(proj_w + (size_t)col * 2048 + kb);
    float4 w1 = *(const float4*)(proj_w + (size_t)col * 2048 + kb + 4);
    float v[8] = {w0.x, w0.y, w0.z, w0.w, w1.x, w1.y, w1.z, w1.w};
    FragU s1, s2, s3;
    #pragma unroll
    for (int p = 0; p < 4; ++p)
        split3pk(v[2*p], v[2*p+1], s1.u[p], s2.u[p], s3.u[p]);
    size_t base = (size_t)ksg * 2048 + t * 512 + l * 8;
    *(short8*)(wp + base)          = s1.s;
    *(short8*)(wp + PB + base)     = s2.s;
    *(short8*)(wp + 2 * PB + base) = s3.s;
}

// ---------------- pack emb (global order) into 3 bf16 B-frag planes ---------
// plane: [nt 0..127][ks 0..1][lane][j]; neuron=nt*16+(l&15), k=ks*32+(l>>4)*8+j
__global__ void embpack_kernel(const float* __restrict__ emb,
                               const float* __restrict__ emb_rel_k,
                               unsigned short* __restrict__ bp)
{
    int idx = blockIdx.x * 256 + threadIdx.x;   // 16384
    int l = idx & 63;
    int ks = (idx >> 6) & 1;
    int nt = idx >> 7;
    int n = nt * 16 + (l & 15);
    const float* src;
    if (n < 1280)      src = emb + (size_t)n * 64;
    else if (n < 1792) src = emb_rel_k + (size_t)(n - 1280) * 64;
    else               src = emb + (size_t)(n - 512) * 64;
    int c0 = ks * 32 + (l >> 4) * 8;
    float4 w0 = *(const float4*)(src + c0);
    float4 w1 = *(const float4*)(src + c0 + 4);
    float v[8] = {w0.x, w0.y, w0.z, w0.w, w1.x, w1.y, w1.z, w1.w};
    FragU s1, s2, s3;
    #pragma unroll
    for (int p = 0; p < 4; ++p)
        split3pk(v[2*p], v[2*p+1], s1.u[p], s2.u[p], s3.u[p]);
    size_t base = ((size_t)nt * 2 + ks) * 512 + l * 8;
    *(short8*)(bp + base)          = s1.s;
    *(short8*)(bp + PB + base)     = s2.s;
    *(short8*)(bp + 2 * PB + base) = s3.s;
}

#define MFMA16(a, b, c) __builtin_amdgcn_mfma_f32_16x16x32_bf16(a, b, c, 0, 0, 0)

// ---------------- proj GEMM via split-bf16 MFMA -----------------------------
// Block: 2 x 16-row tiles x 4-way K-split = 8 waves. Wave owns ONE 16-row tile
// and a 512-K slice (16 k-steps). Per k-step: ALL 12 B frags loaded upfront
// (parallel, latency amortized over the 24-MFMA cluster) + 1-deep A prefetch.
__launch_bounds__(512, 4)
__global__ void proj_kernel(const float* __restrict__ x,
                            const unsigned short* __restrict__ wp,
                            const float* __restrict__ proj_b,
                            unsigned short* __restrict__ hs)
{
    __shared__ float sAcc[8][1024];   // [tile*4+kp][16 rows x 64 cols] = 32 KB
    __shared__ float sH[2][1024];     // reduced h tiles, 8 KB

    const int tid = threadIdx.x;
    const int wave = tid >> 6, lane = tid & 63;
    const int tile = wave >> 2, kp = wave & 3;
    const int g_ = lane >> 4, r_ = lane & 15;
    const int row0 = blockIdx.x * 32 + tile * 16;

    const float* xa = x + (size_t)(row0 + r_) * 2048 + kp * 512 + g_ * 8;

    f32x4 acc[4];
    #pragma unroll
    for (int t = 0; t < 4; ++t) acc[t] = (f32x4){0.f, 0.f, 0.f, 0.f};

    float4 a0 = *(const float4*)(xa);
    float4 a1 = *(const float4*)(xa + 4);

    for (int ks = 0; ks < 16; ++ks) {
        const int ksg = kp * 16 + ks;
        const unsigned short* wb = wp + (size_t)ksg * 2048 + lane * 8;
        // ALL 12 B fragment loads issued upfront (independent -> overlap)
        short8 B1[4], B2[4], B3[4];
        #pragma unroll
        for (int t = 0; t < 4; ++t) {
            B1[t] = *(const short8*)(wb + t * 512);
            B2[t] = *(const short8*)(wb + PB + t * 512);
            B3[t] = *(const short8*)(wb + 2 * PB + t * 512);
        }
        // A prefetch for next k-step
        float4 na0, na1;
        if (ks < 15) {
            na0 = *(const float4*)(xa + (ks + 1) * 32);
            na1 = *(const float4*)(xa + (ks + 1) * 32 + 4);
        }
        // split A (RNE x3 via cvt_pk)
        float av[8] = {a0.x, a0.y, a0.z, a0.w, a1.x, a1.y, a1.z, a1.w};
        FragU A1, A2, A3;
        #pragma unroll
        for (int p = 0; p < 4; ++p)
            split3pk(av[2*p], av[2*p+1], A1.u[p], A2.u[p], A3.u[p]);
        #pragma unroll
        for (int t = 0; t < 4; ++t) {
            acc[t] = MFMA16(A1.s, B1[t], acc[t]);
            acc[t] = MFMA16(A1.s, B2[t], acc[t]);
            acc[t] = MFMA16(A2.s, B1[t], acc[t]);
            acc[t] = MFMA16(A2.s, B2[t], acc[t]);
            acc[t] = MFMA16(A1.s, B3[t], acc[t]);
            acc[t] = MFMA16(A3.s, B1[t], acc[t]);
        }
        a0 = na0; a1 = na1;
    }

    // D: row = g_*4+rr, col = t*16 + r_
    #pragma unroll
    for (int t = 0; t < 4; ++t)
        #pragma unroll
        for (int rr = 0; rr < 4; ++rr)
            sAcc[wave][(g_ * 4 + rr) * 64 + t * 16 + r_] = acc[t][rr];
    __syncthreads();

    // reduce 4 K-partials + bias -> sH; each thread owns 4 elems of 2048
    {
        int i0 = tid * 4;
        int tl = i0 >> 10, wi = i0 & 1023;
        float4 s = *(const float4*)(&sAcc[tl * 4][wi]);
        #pragma unroll
        for (int w = 1; w < 4; ++w) {
            float4 p = *(const float4*)(&sAcc[tl * 4 + w][wi]);
            s.x += p.x; s.y += p.y; s.z += p.z; s.w += p.w;
        }
        float4 bb = *(const float4*)(proj_b + (wi & 63));
        s.x += bb.x; s.y += bb.y; s.z += bb.z; s.w += bb.w;
        *(float4*)(&sH[tl][wi]) = s;
    }
    __syncthreads();

    // pack h tiles into 3 A-frag planes (256 threads: 2 tile x 2 ks x 64 lanes)
    if (tid < 256) {
        int pl = tid & 63;
        int ks = (tid >> 6) & 1;
        int tl = tid >> 7;
        int row = pl & 15;
        int c0 = ks * 32 + (pl >> 4) * 8;
        const float* hb = &sH[tl][row * 64 + c0];
        FragU s1, s2, s3;
        #pragma unroll
        for (int p = 0; p < 4; ++p)
            split3pk(hb[2*p], hb[2*p+1], s1.u[p], s2.u[p], s3.u[p]);
        size_t rg = (size_t)blockIdx.x * 2 + tl;
        size_t base = (rg * 2 + ks) * 512 + pl * 8;
        *(short8*)(hs + base)          = s1.s;
        *(short8*)(hs + PH + base)     = s2.s;
        *(short8*)(hs + 2 * PH + base) = s3.s;
    }
}

// ---------------- routing via MFMA: logits -> segment softmax -> pool -------
// Block: 16 rows, 16 waves (1024 thr); wave w owns neurons [w*128, w*128+128)
// (acc[8] = 32 VGPR). B triples double-buffered across the 16 bursts.
// Segment -> wave ranges: qk w0-3, fv w4-5, q w6-9, k w10-13, val w14-15.
__launch_bounds__(1024, 4)
__global__ void route_kernel(const unsigned short* __restrict__ hs,
                             const unsigned short* __restrict__ bp,
                             const float* __restrict__ imp,
                             const float* __restrict__ invn_g,
                             const float* __restrict__ bonus_g,
                             float* __restrict__ wout)
{
    __shared__ float2 red[16][16];

    const int tid = threadIdx.x;
    const int wave = tid >> 6, lane = tid & 63;
    const int g_ = lane >> 4, r_ = lane & 15;
    const int rowBase = blockIdx.x * 16;
    const int b = rowBase >> 11;
    const int n0 = wave * 128;

    // A-fragments: 2 k-halves x 3 splits = 6 short8 (24 VGPR)
    short8 A1[2], A2[2], A3[2];
    #pragma unroll
    for (int ks = 0; ks < 2; ++ks) {
        size_t base = ((size_t)blockIdx.x * 2 + ks) * 512 + lane * 8;
        A1[ks] = *(const short8*)(hs + base);
        A2[ks] = *(const short8*)(hs + PH + base);
        A3[ks] = *(const short8*)(hs + 2 * PH + base);
    }

    f32x4 acc[8];
    #pragma unroll
    for (int t = 0; t < 8; ++t) acc[t] = (f32x4){0.f, 0.f, 0.f, 0.f};

    // 16 bursts (t 0..7 x ks 0..1), B triple double-buffered
    const int nt0 = wave * 8;
    short8 Bc1, Bc2, Bc3, Bn1, Bn2, Bn3;
    {
        size_t base = ((size_t)nt0 * 2 + 0) * 512 + lane * 8;
        Bc1 = *(const short8*)(bp + base);
        Bc2 = *(const short8*)(bp + PB + base);
        Bc3 = *(const short8*)(bp + 2 * PB + base);
    }
    #pragma unroll
    for (int burst = 0; burst < 16; ++burst) {
        const int t = burst >> 1, ks = burst & 1;
        if (burst < 15) {
            const int tn = (burst + 1) >> 1, ksn = (burst + 1) & 1;
            size_t base = ((size_t)(nt0 + tn) * 2 + ksn) * 512 + lane * 8;
            Bn1 = *(const short8*)(bp + base);
            Bn2 = *(const short8*)(bp + PB + base);
            Bn3 = *(const short8*)(bp + 2 * PB + base);
        }
        acc[t] = MFMA16(A1[ks], Bc1, acc[t]);
        acc[t] = MFMA16(A1[ks], Bc2, acc[t]);
        acc[t] = MFMA16(A2[ks], Bc1, acc[t]);
        acc[t] = MFMA16(A2[ks], Bc2, acc[t]);
        acc[t] = MFMA16(A1[ks], Bc3, acc[t]);
        acc[t] = MFMA16(A3[ks], Bc1, acc[t]);
        Bc1 = Bn1; Bc2 = Bn2; Bc3 = Bn3;
    }

    float inv_[8], bon_[8];
    #pragma unroll
    for (int t = 0; t < 8; ++t) {
        inv_[t] = invn_g[n0 + t * 16 + r_];
        bon_[t] = bonus_g[n0 + t * 16 + r_];
    }

    // pass 1: per row r -> wave-local (max, expsum) -> LDS
    float m_[4], s_[4];
    #pragma unroll
    for (int r = 0; r < 4; ++r) {
        float m = -INFINITY;
        #pragma unroll
        for (int t = 0; t < 8; ++t)
            m = fmaxf(m, fmaf(acc[t][r], inv_[t], bon_[t]));
        #pragma unroll
        for (int d = 1; d <= 8; d <<= 1)
            m = fmaxf(m, __shfl_xor(m, d));
        float s = 0.f;
        #pragma unroll
        for (int t = 0; t < 8; ++t)
            s += __expf(fmaf(acc[t][r], inv_[t], bon_[t]) - m);
        #pragma unroll
        for (int d = 1; d <= 8; d <<= 1)
            s += __shfl_xor(s, d);
        m_[r] = m; s_[r] = s;
        if (r_ == 0) red[g_ * 4 + r][wave] = make_float2(m, s);
    }
    __syncthreads();

    // pass 2: multi-wave segment combine, recompute P, weighted pool
    const int SEG0[16] = {0,0,0,0, 4,4, 6,6,6,6, 10,10,10,10, 14,14};
    const int SEG1[16] = {4,4,4,4, 6,6, 10,10,10,10, 14,14,14,14, 16,16};
    const int s0 = SEG0[wave], s1 = SEG1[wave];

    float accw[8];
    #pragma unroll
    for (int t = 0; t < 8; ++t) accw[t] = 0.f;

    #pragma unroll
    for (int r = 0; r < 4; ++r) {
        const int row = g_ * 4 + r;
        float M = -INFINITY;
        for (int j = s0; j < s1; ++j)
            M = fmaxf(M, red[row][j].x);
        float Z = 0.f;
        for (int j = s0; j < s1; ++j) {
            float2 q = red[row][j];
            Z += q.y * __expf(q.x - M);
        }
        float coef = imp[rowBase + row] / Z * __expf(m_[r] - M);
        #pragma unroll
        for (int t = 0; t < 8; ++t)
            accw[t] = fmaf(coef, __expf(fmaf(acc[t][r], inv_[t], bon_[t]) - m_[r]), accw[t]);
    }

    // reduce the 4 g-groups (rows) per column, then write (2 atomics/thread)
    #pragma unroll
    for (int t = 0; t < 8; ++t) {
        accw[t] += __shfl_xor(accw[t], 16);
        accw[t] += __shfl_xor(accw[t], 32);
    }
    #pragma unroll
    for (int tt = 0; tt < 2; ++tt) {
        int t = g_ * 2 + tt;
        float v = (g_ == 0) ? accw[tt] : (g_ == 1) ? accw[2 + tt]
                : (g_ == 2) ? accw[4 + tt] : accw[6 + tt];
        atomicAdd(&wout[b * 2048 + n0 + t * 16 + r_], v);
    }
}

// ---------------- top-k + softmax + sorted indices, one wave per (b,route) --
__global__ void topk_kernel(const float* __restrict__ w, float* __restrict__ out)
{
    const int lane = threadIdx.x;
    const int blk = blockIdx.x;          // 0..39
    const int b = blk / 5;
    const int route = blk % 5;

    const int segoff[5] = {0, 512, 768, 1280, 1792};
    const int seglen[5] = {512, 256, 512, 512, 256};
    const int kk[5]     = {64, 32, 64, 64, 32};
    const int soff[5]   = {0, 64, 96, 160, 224};
    const int ibase[5]  = {2048, 2560, 2816, 3328, 3840};

    const int L = seglen[route];
    const int K = kk[route];
    const int nv = L >> 6;               // 4 or 8 values per lane

    float v[8];
    #pragma unroll
    for (int i = 0; i < 8; ++i) {
        v[i] = -INFINITY;
        if (i < nv) v[i] = w[b * 2048 + segoff[route] + lane + 64 * i];
    }

    float selv = 0.f; int seli = 0;
    for (int it = 0; it < K; ++it) {
        float bv = -INFINITY; int bi = 0x7fffffff;
        #pragma unroll
        for (int i = 0; i < 8; ++i) {
            int li = lane + 64 * i;
            if (v[i] > bv || (v[i] == bv && li < bi)) { bv = v[i]; bi = li; }
        }
        for (int d = 1; d < 64; d <<= 1) {
            float ov = __shfl_xor(bv, d);
            int   oi = __shfl_xor(bi, d);
            if (ov > bv || (ov == bv && oi < bi)) { bv = ov; bi = oi; }
        }
        if (lane == it) { selv = bv; seli = bi; }
        #pragma unroll
        for (int i = 0; i < 8; ++i)
            if ((bi >> 6) == i && (bi & 63) == lane) v[i] = -INFINITY;
    }

    float m = __shfl(selv, 0);
    float e = (lane < K) ? __expf(selv - m) : 0.f;
    float s = e;
    for (int d = 1; d < 64; d <<= 1) s += __shfl_xor(s, d);
    if (lane < K) out[b * 256 + soff[route] + lane] = e / s;

    int rank = 0;
    for (int j = 0; j < K; ++j) {
        int oj = __shfl(seli, j);
        if (oj < seli) rank++;
    }
    if (lane < K) out[ibase[route] + b * K + rank] = (float)seli;
}

extern "C" void kernel_launch(void* const* d_in, const int* in_sizes, int n_in,
                              void* d_out, int out_size, void* d_ws, size_t ws_size,
                              hipStream_t stream)
{
    const float* x        = (const float*)d_in[0];
    const float* imp      = (const float*)d_in[1];
    const float* proj_w   = (const float*)d_in[2];
    const float* proj_b   = (const float*)d_in[3];
    const float* emb      = (const float*)d_in[4];
    const float* emb_rel  = (const float*)d_in[5];
    const float* ema_qk   = (const float*)d_in[6];
    const float* ema_v    = (const float*)d_in[7];
    const float* ema_rel  = (const float*)d_in[8];
    const float* ema_val  = (const float*)d_in[9];
    float* out = (float*)d_out;

    float* invn  = (float*)d_ws;                       // 2048 f32
    float* bonus = invn + 2048;                        // 2048 f32
    float* wacc  = bonus + 2048;                       // 16384 f32
    unsigned short* wp = (unsigned short*)(wacc + 16384);  // 3*PB u16
    unsigned short* bp = wp + 3 * PB;                  // 3*PB u16
    unsigned short* hs = bp + 3 * PB;                  // 3*PH u16 (6 MB)

    prep_kernel<<<32, 64, 0, stream>>>(emb, emb_rel, ema_qk, ema_v, ema_rel, ema_val, invn, bonus, wacc);
    wtpack3_kernel<<<64, 256, 0, stream>>>(proj_w, wp);
    embpack_kernel<<<64, 256, 0, stream>>>(emb, emb_rel, bp);
    proj_kernel<<<512, 512, 0, stream>>>(x, wp, proj_b, hs);
    route_kernel<<<1024, 1024, 0, stream>>>(hs, bp, imp, invn, bonus, wacc);
    topk_kernel<<<40, 64, 0, stream>>>(wacc, out);
}

// Round 10
// 164.556 us; speedup vs baseline: 1.1026x; 1.1026x over previous
//
#include <hip/hip_runtime.h>
#include <cmath>

typedef __attribute__((ext_vector_type(8))) short short8;
typedef __attribute__((ext_vector_type(4))) float f32x4;

static __device__ __forceinline__ unsigned cvtpk(float lo, float hi) {
    unsigned r;
    asm("v_cvt_pk_bf16_f32 %0, %1, %2" : "=v"(r) : "v"(lo), "v"(hi));
    return r;
}
// 3-level RNE split of a pair of floats -> 3 packed-bf16 dwords; v = s1+s2+s3 + O(2^-27 |v|)
static __device__ __forceinline__ void split3pk(float v0, float v1,
                                                unsigned& o1, unsigned& o2, unsigned& o3) {
    o1 = cvtpk(v0, v1);
    float r0 = v0 - __uint_as_float(o1 << 16);
    float r1 = v1 - __uint_as_float(o1 & 0xffff0000u);
    o2 = cvtpk(r0, r1);
    float q0 = r0 - __uint_as_float(o2 << 16);
    float q1 = r1 - __uint_as_float(o2 & 0xffff0000u);
    o3 = cvtpk(q0, q1);
}

union FragU { short8 s; unsigned u[4]; };

#define PH 1048576   // h plane elems (16384*64)
#define PB 131072    // emb/W plane elems (2048*64)

// ---------------- prep: zero wacc + inv-norms + excitability bonus ----------
// global order: [qk 0..511][fv 512..767][q 768..1279][k(rel) 1280..1791][val 1792..2047]
__global__ void prep_kernel(const float* __restrict__ emb,
                            const float* __restrict__ emb_rel_k,
                            const float* __restrict__ ema_qk,
                            const float* __restrict__ ema_v,
                            const float* __restrict__ ema_rel,
                            const float* __restrict__ ema_val,
                            float* __restrict__ invn,
                            float* __restrict__ bonus,
                            float* __restrict__ wacc)
{
    int n = blockIdx.x * 64 + threadIdx.x;   // 32 x 64 -> 2048
    {
        float4 z = {0.f, 0.f, 0.f, 0.f};
        *(float4*)(wacc + (size_t)n * 8)     = z;
        *(float4*)(wacc + (size_t)n * 8 + 4) = z;
    }
    const float* row;
    float ema;
    if (n < 512)       { row = emb + (size_t)n * 64;                ema = ema_qk[n]; }
    else if (n < 768)  { row = emb + (size_t)n * 64;                ema = ema_v[n - 512]; }
    else if (n < 1280) { row = emb + (size_t)n * 64;                ema = ema_rel[n - 768]; }
    else if (n < 1792) { row = emb_rel_k + (size_t)(n - 1280) * 64; ema = ema_rel[n - 1280]; }
    else               { row = emb + (size_t)(n - 512) * 64;        ema = ema_val[n - 1792]; }
    float s = 0.f;
    #pragma unroll
    for (int k = 0; k < 64; k += 4) {
        float4 v = *(const float4*)(row + k);
        s += v.x*v.x + v.y*v.y + v.z*v.z + v.w*v.w;
    }
    invn[n] = 1.0f / sqrtf(s);
    float ex = 1.0f - ema * (1.0f / 1.5f);   // TAU = 1.5
    ex = fminf(fmaxf(ex, 0.f), 1.f);
    bonus[n] = ex * 1.0f;                    // EXC_W = 1.0
}

// ---------------- pack W into 3 bf16 split planes, MFMA B-fragment order ----
// plane: [ksg 0..63][t 0..3][lane 0..63][j 0..7]; col=16t+(l&15), k=ksg*32+(l>>4)*8+j
__global__ void wtpack3_kernel(const float* __restrict__ proj_w, unsigned short* __restrict__ wp)
{
    int idx = blockIdx.x * 256 + threadIdx.x;   // 16384
    int l = idx & 63;
    int t = (idx >> 6) & 3;
    int ksg = idx >> 8;
    int col = t * 16 + (l & 15);
    int kb = ksg * 32 + (l >> 4) * 8;
    float4 w0 = *(const float4*)(proj_w + (size_t)col * 2048 + kb);
    float4 w1 = *(const float4*)(proj_w + (size_t)col * 2048 + kb + 4);
    float v[8] = {w0.x, w0.y, w0.z, w0.w, w1.x, w1.y, w1.z, w1.w};
    FragU s1, s2, s3;
    #pragma unroll
    for (int p = 0; p < 4; ++p)
        split3pk(v[2*p], v[2*p+1], s1.u[p], s2.u[p], s3.u[p]);
    size_t base = (size_t)ksg * 2048 + t * 512 + l * 8;
    *(short8*)(wp + base)          = s1.s;
    *(short8*)(wp + PB + base)     = s2.s;
    *(short8*)(wp + 2 * PB + base) = s3.s;
}

// ---------------- pack emb (global order) into 3 bf16 B-frag planes ---------
// plane: [nt 0..127][ks 0..1][lane][j]; neuron=nt*16+(l&15), k=ks*32+(l>>4)*8+j
__global__ void embpack_kernel(const float* __restrict__ emb,
                               const float* __restrict__ emb_rel_k,
                               unsigned short* __restrict__ bp)
{
    int idx = blockIdx.x * 256 + threadIdx.x;   // 16384
    int l = idx & 63;
    int ks = (idx >> 6) & 1;
    int nt = idx >> 7;
    int n = nt * 16 + (l & 15);
    const float* src;
    if (n < 1280)      src = emb + (size_t)n * 64;
    else if (n < 1792) src = emb_rel_k + (size_t)(n - 1280) * 64;
    else               src = emb + (size_t)(n - 512) * 64;
    int c0 = ks * 32 + (l >> 4) * 8;
    float4 w0 = *(const float4*)(src + c0);
    float4 w1 = *(const float4*)(src + c0 + 4);
    float v[8] = {w0.x, w0.y, w0.z, w0.w, w1.x, w1.y, w1.z, w1.w};
    FragU s1, s2, s3;
    #pragma unroll
    for (int p = 0; p < 4; ++p)
        split3pk(v[2*p], v[2*p+1], s1.u[p], s2.u[p], s3.u[p]);
    size_t base = ((size_t)nt * 2 + ks) * 512 + l * 8;
    *(short8*)(bp + base)          = s1.s;
    *(short8*)(bp + PB + base)     = s2.s;
    *(short8*)(bp + 2 * PB + base) = s3.s;
}

#define MFMA16(a, b, c) __builtin_amdgcn_mfma_f32_16x16x32_bf16(a, b, c, 0, 0, 0)
#define SCHED_FENCE()   __builtin_amdgcn_sched_barrier(0)

// ---------------- proj GEMM via split-bf16 MFMA -----------------------------
// Block: 2 x 16-row tiles x 4-way K-split = 8 waves. Wave owns ONE 16-row tile
// and a 512-K slice (16 k-steps). Per k-step: {12 B loads + 2 A prefetch}
// pinned BEFORE the MFMA cluster by sched_barrier(0) -> latency paid once.
__launch_bounds__(512, 4)
__global__ void proj_kernel(const float* __restrict__ x,
                            const unsigned short* __restrict__ wp,
                            const float* __restrict__ proj_b,
                            unsigned short* __restrict__ hs)
{
    __shared__ float sAcc[8][1024];   // [tile*4+kp][16 rows x 64 cols] = 32 KB
    __shared__ float sH[2][1024];     // reduced h tiles, 8 KB

    const int tid = threadIdx.x;
    const int wave = tid >> 6, lane = tid & 63;
    const int tile = wave >> 2, kp = wave & 3;
    const int g_ = lane >> 4, r_ = lane & 15;
    const int row0 = blockIdx.x * 32 + tile * 16;

    const float* xa = x + (size_t)(row0 + r_) * 2048 + kp * 512 + g_ * 8;

    f32x4 acc[4];
    #pragma unroll
    for (int t = 0; t < 4; ++t) acc[t] = (f32x4){0.f, 0.f, 0.f, 0.f};

    float4 a0 = *(const float4*)(xa);
    float4 a1 = *(const float4*)(xa + 4);

    for (int ks = 0; ks < 16; ++ks) {
        const int ksg = kp * 16 + ks;
        const unsigned short* wb = wp + (size_t)ksg * 2048 + lane * 8;
        // ALL 12 B fragment loads + A prefetch issued, then fenced
        short8 B1[4], B2[4], B3[4];
        #pragma unroll
        for (int t = 0; t < 4; ++t) {
            B1[t] = *(const short8*)(wb + t * 512);
            B2[t] = *(const short8*)(wb + PB + t * 512);
            B3[t] = *(const short8*)(wb + 2 * PB + t * 512);
        }
        float4 na0, na1;
        if (ks < 15) {
            na0 = *(const float4*)(xa + (ks + 1) * 32);
            na1 = *(const float4*)(xa + (ks + 1) * 32 + 4);
        }
        SCHED_FENCE();   // loads may not sink past this point
        // split A (RNE x3 via cvt_pk)
        float av[8] = {a0.x, a0.y, a0.z, a0.w, a1.x, a1.y, a1.z, a1.w};
        FragU A1, A2, A3;
        #pragma unroll
        for (int p = 0; p < 4; ++p)
            split3pk(av[2*p], av[2*p+1], A1.u[p], A2.u[p], A3.u[p]);
        #pragma unroll
        for (int t = 0; t < 4; ++t) {
            acc[t] = MFMA16(A1.s, B1[t], acc[t]);
            acc[t] = MFMA16(A1.s, B2[t], acc[t]);
            acc[t] = MFMA16(A2.s, B1[t], acc[t]);
            acc[t] = MFMA16(A2.s, B2[t], acc[t]);
            acc[t] = MFMA16(A1.s, B3[t], acc[t]);
            acc[t] = MFMA16(A3.s, B1[t], acc[t]);
        }
        a0 = na0; a1 = na1;
    }

    // D: row = g_*4+rr, col = t*16 + r_
    #pragma unroll
    for (int t = 0; t < 4; ++t)
        #pragma unroll
        for (int rr = 0; rr < 4; ++rr)
            sAcc[wave][(g_ * 4 + rr) * 64 + t * 16 + r_] = acc[t][rr];
    __syncthreads();

    // reduce 4 K-partials + bias -> sH; each thread owns 4 elems of 2048
    {
        int i0 = tid * 4;
        int tl = i0 >> 10, wi = i0 & 1023;
        float4 s = *(const float4*)(&sAcc[tl * 4][wi]);
        #pragma unroll
        for (int w = 1; w < 4; ++w) {
            float4 p = *(const float4*)(&sAcc[tl * 4 + w][wi]);
            s.x += p.x; s.y += p.y; s.z += p.z; s.w += p.w;
        }
        float4 bb = *(const float4*)(proj_b + (wi & 63));
        s.x += bb.x; s.y += bb.y; s.z += bb.z; s.w += bb.w;
        *(float4*)(&sH[tl][wi]) = s;
    }
    __syncthreads();

    // pack h tiles into 3 A-frag planes (256 threads: 2 tile x 2 ks x 64 lanes)
    if (tid < 256) {
        int pl = tid & 63;
        int ks = (tid >> 6) & 1;
        int tl = tid >> 7;
        int row = pl & 15;
        int c0 = ks * 32 + (pl >> 4) * 8;
        const float* hb = &sH[tl][row * 64 + c0];
        FragU s1, s2, s3;
        #pragma unroll
        for (int p = 0; p < 4; ++p)
            split3pk(hb[2*p], hb[2*p+1], s1.u[p], s2.u[p], s3.u[p]);
        size_t rg = (size_t)blockIdx.x * 2 + tl;
        size_t base = (rg * 2 + ks) * 512 + pl * 8;
        *(short8*)(hs + base)          = s1.s;
        *(short8*)(hs + PH + base)     = s2.s;
        *(short8*)(hs + 2 * PH + base) = s3.s;
    }
}

// ---------------- routing via MFMA: logits -> segment softmax -> pool -------
// Block: 16 rows, 8 waves (512 thr); wave w owns neurons [w*256, w*256+256).
// B triples 2-deep double-buffered (even/odd reg sets) + sched fences.
// Segments align to waves: 0-1=qk, 2=fv, 3-4=q, 5-6=k, 7=val.
__launch_bounds__(512, 4)
__global__ void route_kernel(const unsigned short* __restrict__ hs,
                             const unsigned short* __restrict__ bp,
                             const float* __restrict__ imp,
                             const float* __restrict__ invn_g,
                             const float* __restrict__ bonus_g,
                             float* __restrict__ wout)
{
    __shared__ float2 red[16][8];

    const int tid = threadIdx.x;
    const int wave = tid >> 6, lane = tid & 63;
    const int g_ = lane >> 4, r_ = lane & 15;
    const int rowBase = blockIdx.x * 16;
    const int b = rowBase >> 11;
    const int n0 = wave * 256;

    // A-fragments: 2 k-halves x 3 splits = 6 short8 (24 VGPR)
    short8 A1[2], A2[2], A3[2];
    #pragma unroll
    for (int ks = 0; ks < 2; ++ks) {
        size_t base = ((size_t)blockIdx.x * 2 + ks) * 512 + lane * 8;
        A1[ks] = *(const short8*)(hs + base);
        A2[ks] = *(const short8*)(hs + PH + base);
        A3[ks] = *(const short8*)(hs + 2 * PH + base);
    }

    f32x4 acc[16];
    #pragma unroll
    for (int t = 0; t < 16; ++t) acc[t] = (f32x4){0.f, 0.f, 0.f, 0.f};

    // 32 bursts (t 0..15 x ks 0..1); B triple double-buffered even/odd
    const int nt0 = wave * 16;
    const size_t lb = lane * 8;
    short8 Ea1, Ea2, Ea3, Eb1, Eb2, Eb3;
    {
        size_t base = ((size_t)nt0 * 2) * 512 + lb;
        Ea1 = *(const short8*)(bp + base);
        Ea2 = *(const short8*)(bp + PB + base);
        Ea3 = *(const short8*)(bp + 2 * PB + base);
    }
    #pragma unroll
    for (int burst = 0; burst < 32; ++burst) {
        const int t = burst >> 1, ks = burst & 1;
        if (burst < 31) {
            size_t base = ((size_t)(nt0 + ((burst + 1) >> 1)) * 2 + ((burst + 1) & 1)) * 512 + lb;
            if (burst & 1) {
                Ea1 = *(const short8*)(bp + base);
                Ea2 = *(const short8*)(bp + PB + base);
                Ea3 = *(const short8*)(bp + 2 * PB + base);
            } else {
                Eb1 = *(const short8*)(bp + base);
                Eb2 = *(const short8*)(bp + PB + base);
                Eb3 = *(const short8*)(bp + 2 * PB + base);
            }
        }
        SCHED_FENCE();   // prefetch must issue before this burst's MFMAs
        if (burst & 1) {
            acc[t] = MFMA16(A1[ks], Eb1, acc[t]);
            acc[t] = MFMA16(A1[ks], Eb2, acc[t]);
            acc[t] = MFMA16(A2[ks], Eb1, acc[t]);
            acc[t] = MFMA16(A2[ks], Eb2, acc[t]);
            acc[t] = MFMA16(A1[ks], Eb3, acc[t]);
            acc[t] = MFMA16(A3[ks], Eb1, acc[t]);
        } else {
            acc[t] = MFMA16(A1[ks], Ea1, acc[t]);
            acc[t] = MFMA16(A1[ks], Ea2, acc[t]);
            acc[t] = MFMA16(A2[ks], Ea1, acc[t]);
            acc[t] = MFMA16(A2[ks], Ea2, acc[t]);
            acc[t] = MFMA16(A1[ks], Ea3, acc[t]);
            acc[t] = MFMA16(A3[ks], Ea1, acc[t]);
        }
    }

    float inv_[16], bon_[16];
    #pragma unroll
    for (int t = 0; t < 16; ++t) {
        inv_[t] = invn_g[n0 + t * 16 + r_];
        bon_[t] = bonus_g[n0 + t * 16 + r_];
    }

    // pass 1: per row r -> wave-local (max, expsum) -> LDS
    float m_[4], s_[4];
    #pragma unroll
    for (int r = 0; r < 4; ++r) {
        float m = -INFINITY;
        #pragma unroll
        for (int t = 0; t < 16; ++t)
            m = fmaxf(m, fmaf(acc[t][r], inv_[t], bon_[t]));
        #pragma unroll
        for (int d = 1; d <= 8; d <<= 1)
            m = fmaxf(m, __shfl_xor(m, d));
        float s = 0.f;
        #pragma unroll
        for (int t = 0; t < 16; ++t)
            s += __expf(fmaf(acc[t][r], inv_[t], bon_[t]) - m);
        #pragma unroll
        for (int d = 1; d <= 8; d <<= 1)
            s += __shfl_xor(s, d);
        m_[r] = m; s_[r] = s;
        if (r_ == 0) red[g_ * 4 + r][wave] = make_float2(m, s);
    }
    __syncthreads();

    // pass 2: cross-wave combine, recompute P, weighted pool
    const unsigned PTAB = 0xF5634F01u;
    const int pn = (PTAB >> (wave * 4)) & 0xF;
    float accw[16];
    #pragma unroll
    for (int t = 0; t < 16; ++t) accw[t] = 0.f;

    #pragma unroll
    for (int r = 0; r < 4; ++r) {
        const int row = g_ * 4 + r;
        float m = m_[r], s = s_[r];
        float M = m, Z = s;
        if (pn != 0xF) {
            float2 q = red[row][pn];
            M = fmaxf(m, q.x);
            Z = s * __expf(m - M) + q.y * __expf(q.x - M);
        }
        float coef = imp[rowBase + row] / Z * __expf(m - M);
        #pragma unroll
        for (int t = 0; t < 16; ++t)
            accw[t] = fmaf(coef, __expf(fmaf(acc[t][r], inv_[t], bon_[t]) - m), accw[t]);
    }

    // reduce the 4 g-groups (rows) per column, then write
    #pragma unroll
    for (int t = 0; t < 16; ++t) {
        accw[t] += __shfl_xor(accw[t], 16);
        accw[t] += __shfl_xor(accw[t], 32);
    }
    #pragma unroll
    for (int tt = 0; tt < 4; ++tt) {
        int t = g_ * 4 + tt;
        float v = (tt == 0) ? accw[g_ * 4] : (tt == 1) ? accw[g_ * 4 + 1]
                : (tt == 2) ? accw[g_ * 4 + 2] : accw[g_ * 4 + 3];
        atomicAdd(&wout[b * 2048 + n0 + t * 16 + r_], v);
    }
}

// ---------------- top-k + softmax + sorted indices, one wave per (b,route) --
__global__ void topk_kernel(const float* __restrict__ w, float* __restrict__ out)
{
    const int lane = threadIdx.x;
    const int blk = blockIdx.x;          // 0..39
    const int b = blk / 5;
    const int route = blk % 5;

    const int segoff[5] = {0, 512, 768, 1280, 1792};
    const int seglen[5] = {512, 256, 512, 512, 256};
    const int kk[5]     = {64, 32, 64, 64, 32};
    const int soff[5]   = {0, 64, 96, 160, 224};
    const int ibase[5]  = {2048, 2560, 2816, 3328, 3840};

    const int L = seglen[route];
    const int K = kk[route];
    const int nv = L >> 6;               // 4 or 8 values per lane

    float v[8];
    #pragma unroll
    for (int i = 0; i < 8; ++i) {
        v[i] = -INFINITY;
        if (i < nv) v[i] = w[b * 2048 + segoff[route] + lane + 64 * i];
    }

    float selv = 0.f; int seli = 0;
    for (int it = 0; it < K; ++it) {
        float bv = -INFINITY; int bi = 0x7fffffff;
        #pragma unroll
        for (int i = 0; i < 8; ++i) {
            int li = lane + 64 * i;
            if (v[i] > bv || (v[i] == bv && li < bi)) { bv = v[i]; bi = li; }
        }
        for (int d = 1; d < 64; d <<= 1) {
            float ov = __shfl_xor(bv, d);
            int   oi = __shfl_xor(bi, d);
            if (ov > bv || (ov == bv && oi < bi)) { bv = ov; bi = oi; }
        }
        if (lane == it) { selv = bv; seli = bi; }
        #pragma unroll
        for (int i = 0; i < 8; ++i)
            if ((bi >> 6) == i && (bi & 63) == lane) v[i] = -INFINITY;
    }

    float m = __shfl(selv, 0);
    float e = (lane < K) ? __expf(selv - m) : 0.f;
    float s = e;
    for (int d = 1; d < 64; d <<= 1) s += __shfl_xor(s, d);
    if (lane < K) out[b * 256 + soff[route] + lane] = e / s;

    int rank = 0;
    for (int j = 0; j < K; ++j) {
        int oj = __shfl(seli, j);
        if (oj < seli) rank++;
    }
    if (lane < K) out[ibase[route] + b * K + rank] = (float)seli;
}

extern "C" void kernel_launch(void* const* d_in, const int* in_sizes, int n_in,
                              void* d_out, int out_size, void* d_ws, size_t ws_size,
                              hipStream_t stream)
{
    const float* x        = (const float*)d_in[0];
    const float* imp      = (const float*)d_in[1];
    const float* proj_w   = (const float*)d_in[2];
    const float* proj_b   = (const float*)d_in[3];
    const float* emb      = (const float*)d_in[4];
    const float* emb_rel  = (const float*)d_in[5];
    const float* ema_qk   = (const float*)d_in[6];
    const float* ema_v    = (const float*)d_in[7];
    const float* ema_rel  = (const float*)d_in[8];
    const float* ema_val  = (const float*)d_in[9];
    float* out = (float*)d_out;

    float* invn  = (float*)d_ws;                       // 2048 f32
    float* bonus = invn + 2048;                        // 2048 f32
    float* wacc  = bonus + 2048;                       // 16384 f32
    unsigned short* wp = (unsigned short*)(wacc + 16384);  // 3*PB u16
    unsigned short* bp = wp + 3 * PB;                  // 3*PB u16
    unsigned short* hs = bp + 3 * PB;                  // 3*PH u16 (6 MB)

    prep_kernel<<<32, 64, 0, stream>>>(emb, emb_rel, ema_qk, ema_v, ema_rel, ema_val, invn, bonus, wacc);
    wtpack3_kernel<<<64, 256, 0, stream>>>(proj_w, wp);
    embpack_kernel<<<64, 256, 0, stream>>>(emb, emb_rel, bp);
    proj_kernel<<<512, 512, 0, stream>>>(x, wp, proj_b, hs);
    route_kernel<<<1024, 512, 0, stream>>>(hs, bp, imp, invn, bonus, wacc);
    topk_kernel<<<40, 64, 0, stream>>>(wacc, out);
}

// Round 11
// 153.183 us; speedup vs baseline: 1.1845x; 1.0742x over previous
//
#include <hip/hip_runtime.h>
#include <cmath>

typedef __attribute__((ext_vector_type(8))) short short8;
typedef __attribute__((ext_vector_type(4))) float f32x4;

static __device__ __forceinline__ unsigned cvtpk(float lo, float hi) {
    unsigned r;
    asm("v_cvt_pk_bf16_f32 %0, %1, %2" : "=v"(r) : "v"(lo), "v"(hi));
    return r;
}
// 3-level RNE split of a pair of floats -> 3 packed-bf16 dwords; v = s1+s2+s3 + O(2^-27 |v|)
static __device__ __forceinline__ void split3pk(float v0, float v1,
                                                unsigned& o1, unsigned& o2, unsigned& o3) {
    o1 = cvtpk(v0, v1);
    float r0 = v0 - __uint_as_float(o1 << 16);
    float r1 = v1 - __uint_as_float(o1 & 0xffff0000u);
    o2 = cvtpk(r0, r1);
    float q0 = r0 - __uint_as_float(o2 << 16);
    float q1 = r1 - __uint_as_float(o2 & 0xffff0000u);
    o3 = cvtpk(q0, q1);
}

union FragU { short8 s; unsigned u[4]; };

#define PH 1048576   // h plane elems (16384*64)
#define PB 131072    // emb/W plane elems (2048*64)

// ---------------- prep: zero wacc + inv-norms + excitability bonus ----------
// global order: [qk 0..511][fv 512..767][q 768..1279][k(rel) 1280..1791][val 1792..2047]
__global__ void prep_kernel(const float* __restrict__ emb,
                            const float* __restrict__ emb_rel_k,
                            const float* __restrict__ ema_qk,
                            const float* __restrict__ ema_v,
                            const float* __restrict__ ema_rel,
                            const float* __restrict__ ema_val,
                            float* __restrict__ invn,
                            float* __restrict__ bonus,
                            float* __restrict__ wacc)
{
    int n = blockIdx.x * 64 + threadIdx.x;   // 32 x 64 -> 2048
    {
        float4 z = {0.f, 0.f, 0.f, 0.f};
        *(float4*)(wacc + (size_t)n * 8)     = z;
        *(float4*)(wacc + (size_t)n * 8 + 4) = z;
    }
    const float* row;
    float ema;
    if (n < 512)       { row = emb + (size_t)n * 64;                ema = ema_qk[n]; }
    else if (n < 768)  { row = emb + (size_t)n * 64;                ema = ema_v[n - 512]; }
    else if (n < 1280) { row = emb + (size_t)n * 64;                ema = ema_rel[n - 768]; }
    else if (n < 1792) { row = emb_rel_k + (size_t)(n - 1280) * 64; ema = ema_rel[n - 1280]; }
    else               { row = emb + (size_t)(n - 512) * 64;        ema = ema_val[n - 1792]; }
    float s = 0.f;
    #pragma unroll
    for (int k = 0; k < 64; k += 4) {
        float4 v = *(const float4*)(row + k);
        s += v.x*v.x + v.y*v.y + v.z*v.z + v.w*v.w;
    }
    invn[n] = 1.0f / sqrtf(s);
    float ex = 1.0f - ema * (1.0f / 1.5f);   // TAU = 1.5
    ex = fminf(fmaxf(ex, 0.f), 1.f);
    bonus[n] = ex * 1.0f;                    // EXC_W = 1.0
}

// ---------------- pack W into 3 bf16 split planes, MFMA B-fragment order ----
// plane: [ksg 0..63][t 0..3][lane 0..63][j 0..7]; col=16t+(l&15), k=ksg*32+(l>>4)*8+j
__global__ void wtpack3_kernel(const float* __restrict__ proj_w, unsigned short* __restrict__ wp)
{
    int idx = blockIdx.x * 256 + threadIdx.x;   // 16384
    int l = idx & 63;
    int t = (idx >> 6) & 3;
    int ksg = idx >> 8;
    int col = t * 16 + (l & 15);
    int kb = ksg * 32 + (l >> 4) * 8;
    float4 w0 = *(const float4*)(proj_w + (size_t)col * 2048 + kb);
    float4 w1 = *(const float4*)(proj_w + (size_t)col * 2048 + kb + 4);
    float v[8] = {w0.x, w0.y, w0.z, w0.w, w1.x, w1.y, w1.z, w1.w};
    FragU s1, s2, s3;
    #pragma unroll
    for (int p = 0; p < 4; ++p)
        split3pk(v[2*p], v[2*p+1], s1.u[p], s2.u[p], s3.u[p]);
    size_t base = (size_t)ksg * 2048 + t * 512 + l * 8;
    *(short8*)(wp + base)          = s1.s;
    *(short8*)(wp + PB + base)     = s2.s;
    *(short8*)(wp + 2 * PB + base) = s3.s;
}

// ---------------- pack emb (global order) into 3 bf16 B-frag planes ---------
// plane: [nt 0..127][ks 0..1][lane][j]; neuron=nt*16+(l&15), k=ks*32+(l>>4)*8+j
__global__ void embpack_kernel(const float* __restrict__ emb,
                               const float* __restrict__ emb_rel_k,
                               unsigned short* __restrict__ bp)
{
    int idx = blockIdx.x * 256 + threadIdx.x;   // 16384
    int l = idx & 63;
    int ks = (idx >> 6) & 1;
    int nt = idx >> 7;
    int n = nt * 16 + (l & 15);
    const float* src;
    if (n < 1280)      src = emb + (size_t)n * 64;
    else if (n < 1792) src = emb_rel_k + (size_t)(n - 1280) * 64;
    else               src = emb + (size_t)(n - 512) * 64;
    int c0 = ks * 32 + (l >> 4) * 8;
    float4 w0 = *(const float4*)(src + c0);
    float4 w1 = *(const float4*)(src + c0 + 4);
    float v[8] = {w0.x, w0.y, w0.z, w0.w, w1.x, w1.y, w1.z, w1.w};
    FragU s1, s2, s3;
    #pragma unroll
    for (int p = 0; p < 4; ++p)
        split3pk(v[2*p], v[2*p+1], s1.u[p], s2.u[p], s3.u[p]);
    size_t base = ((size_t)nt * 2 + ks) * 512 + l * 8;
    *(short8*)(bp + base)          = s1.s;
    *(short8*)(bp + PB + base)     = s2.s;
    *(short8*)(bp + 2 * PB + base) = s3.s;
}

#define MFMA16(a, b, c) __builtin_amdgcn_mfma_f32_16x16x32_bf16(a, b, c, 0, 0, 0)

// ---------------- proj GEMM via split-bf16 MFMA, LDS-staged shared B --------
// Block: 256 thr = 4 waves (2 row-tiles x 2 K-halves), 32 rows, grid 512.
// Per k-step: block reg-stages the 24 KB B slab (2 kh x 3 planes x 4 KB,
// linear copy) into a double buffer, ONE barrier per k-step; each wave
// ds_reads its 12 frags (w0/w1 share slab kh0, w2/w3 kh1). A direct + 1-deep.
__launch_bounds__(256, 2)
__global__ void proj_kernel(const float* __restrict__ x,
                            const unsigned short* __restrict__ wp,
                            const float* __restrict__ proj_b,
                            unsigned short* __restrict__ hs)
{
    __shared__ float sB[2][6144];   // [dbuf][kh 2][plane 3][t 4][lane 64 x 4f] = 48 KB
    float* fl = &sB[0][0];          // epilogue alias (12288 floats)

    const int tid = threadIdx.x;
    const int wave = tid >> 6, lane = tid & 63;
    const int rt = wave & 1, kh = wave >> 1;
    const int g_ = lane >> 4, r_ = lane & 15;
    const int row0 = blockIdx.x * 32 + rt * 16;

    const float* xa = x + (size_t)(row0 + r_) * 2048 + kh * 1024 + g_ * 8;

    f32x4 acc[4];
    #pragma unroll
    for (int t = 0; t < 4; ++t) acc[t] = (f32x4){0.f, 0.f, 0.f, 0.f};

    // prologue: stage k-step 0 into buf 0
    {
        float4 v[6];
        #pragma unroll
        for (int i = 0; i < 6; ++i)
            v[i] = *(const float4*)(wp + (size_t)(i % 3) * PB
                                      + (size_t)((i / 3) * 32) * 2048 + tid * 8);
        #pragma unroll
        for (int i = 0; i < 6; ++i)
            *(float4*)(&sB[0][i * 1024 + tid * 4]) = v[i];
    }
    __syncthreads();

    float4 a0 = *(const float4*)(xa);
    float4 a1 = *(const float4*)(xa + 4);
    int cur = 0;

    for (int ks = 0; ks < 32; ++ks) {
        // issue next-slab global loads early (land after MFMAs)
        float4 v[6];
        if (ks < 31) {
            #pragma unroll
            for (int i = 0; i < 6; ++i)
                v[i] = *(const float4*)(wp + (size_t)(i % 3) * PB
                                          + (size_t)((i / 3) * 32 + ks + 1) * 2048 + tid * 8);
        }
        // A prefetch
        float4 na0, na1;
        if (ks < 31) {
            na0 = *(const float4*)(xa + (ks + 1) * 32);
            na1 = *(const float4*)(xa + (ks + 1) * 32 + 4);
        }
        // B frags from LDS (slab for this wave's kh)
        const float* bb = fl + (size_t)cur * 6144 + kh * 3072;
        short8 B1[4], B2[4], B3[4];
        #pragma unroll
        for (int t = 0; t < 4; ++t) {
            B1[t] = *(const short8*)(bb + t * 256 + lane * 4);
            B2[t] = *(const short8*)(bb + 1024 + t * 256 + lane * 4);
            B3[t] = *(const short8*)(bb + 2048 + t * 256 + lane * 4);
        }
        // split A (RNE x3 via cvt_pk) -- bit-identical to prior rounds
        float av[8] = {a0.x, a0.y, a0.z, a0.w, a1.x, a1.y, a1.z, a1.w};
        FragU A1, A2, A3;
        #pragma unroll
        for (int p = 0; p < 4; ++p)
            split3pk(av[2*p], av[2*p+1], A1.u[p], A2.u[p], A3.u[p]);
        #pragma unroll
        for (int t = 0; t < 4; ++t) {
            acc[t] = MFMA16(A1.s, B1[t], acc[t]);
            acc[t] = MFMA16(A1.s, B2[t], acc[t]);
            acc[t] = MFMA16(A2.s, B1[t], acc[t]);
            acc[t] = MFMA16(A2.s, B2[t], acc[t]);
            acc[t] = MFMA16(A1.s, B3[t], acc[t]);
            acc[t] = MFMA16(A3.s, B1[t], acc[t]);
        }
        // land staged regs into the other buffer; one barrier per k-step
        if (ks < 31) {
            #pragma unroll
            for (int i = 0; i < 6; ++i)
                *(float4*)(&sB[cur ^ 1][i * 1024 + tid * 4]) = v[i];
            __syncthreads();
            cur ^= 1;
        }
        a0 = na0; a1 = na1;
    }

    __syncthreads();   // staging buffer now reusable for the reduce

    // D: row = g_*4+rr, col = t*16 + r_ ; partial at fl[wave*1024 + ...]
    #pragma unroll
    for (int t = 0; t < 4; ++t)
        #pragma unroll
        for (int rr = 0; rr < 4; ++rr)
            fl[wave * 1024 + (g_ * 4 + rr) * 64 + t * 16 + r_] = acc[t][rr];
    __syncthreads();

    // reduce 2 K-halves + bias -> fl[4096 + tl*1024]; thread owns 4 elems x 2 tiles
    {
        int i0 = tid * 4;
        float4 bb4 = *(const float4*)(proj_b + (i0 & 63));
        #pragma unroll
        for (int tl = 0; tl < 2; ++tl) {
            float4 p0 = *(const float4*)(&fl[tl * 1024 + i0]);        // kh0 (wave tl)
            float4 p1 = *(const float4*)(&fl[(2 + tl) * 1024 + i0]);  // kh1 (wave 2+tl)
            float4 r;
            r.x = p0.x + p1.x + bb4.x; r.y = p0.y + p1.y + bb4.y;
            r.z = p0.z + p1.z + bb4.z; r.w = p0.w + p1.w + bb4.w;
            *(float4*)(&fl[4096 + tl * 1024 + i0]) = r;
        }
    }
    __syncthreads();

    // pack h tiles into 3 A-frag planes (256 threads: 2 tile x 2 ks x 64 lanes)
    {
        int pl = tid & 63;
        int ks = (tid >> 6) & 1;
        int tl = tid >> 7;
        int row = pl & 15;
        int c0 = ks * 32 + (pl >> 4) * 8;
        const float* hb = &fl[4096 + tl * 1024 + row * 64 + c0];
        FragU s1, s2, s3;
        #pragma unroll
        for (int p = 0; p < 4; ++p)
            split3pk(hb[2*p], hb[2*p+1], s1.u[p], s2.u[p], s3.u[p]);
        size_t rg = (size_t)blockIdx.x * 2 + tl;
        size_t base = (rg * 2 + ks) * 512 + pl * 8;
        *(short8*)(hs + base)          = s1.s;
        *(short8*)(hs + PH + base)     = s2.s;
        *(short8*)(hs + 2 * PH + base) = s3.s;
    }
}

// ---------------- routing via MFMA (round-8 form: best measured) ------------
// Block: 16 rows, 8 waves (512 thr); wave w owns neurons [w*256, w*256+256).
// Segments align to waves: 0-1=qk, 2=fv, 3-4=q, 5-6=k, 7=val.
__launch_bounds__(512, 4)
__global__ void route_kernel(const unsigned short* __restrict__ hs,
                             const unsigned short* __restrict__ bp,
                             const float* __restrict__ imp,
                             const float* __restrict__ invn_g,
                             const float* __restrict__ bonus_g,
                             float* __restrict__ wout)
{
    __shared__ float2 red[16][8];

    const int tid = threadIdx.x;
    const int wave = tid >> 6, lane = tid & 63;
    const int g_ = lane >> 4, r_ = lane & 15;
    const int rowBase = blockIdx.x * 16;
    const int b = rowBase >> 11;
    const int n0 = wave * 256;

    // A-fragments: 2 k-halves x 3 splits = 6 short8 (24 VGPR)
    short8 A1[2], A2[2], A3[2];
    #pragma unroll
    for (int ks = 0; ks < 2; ++ks) {
        size_t base = ((size_t)blockIdx.x * 2 + ks) * 512 + lane * 8;
        A1[ks] = *(const short8*)(hs + base);
        A2[ks] = *(const short8*)(hs + PH + base);
        A3[ks] = *(const short8*)(hs + 2 * PH + base);
    }

    f32x4 acc[16];
    #pragma unroll
    for (int t = 0; t < 16; ++t) acc[t] = (f32x4){0.f, 0.f, 0.f, 0.f};

    #pragma unroll
    for (int t = 0; t < 16; ++t) {
        const int nt = wave * 16 + t;
        #pragma unroll
        for (int ks = 0; ks < 2; ++ks) {
            size_t base = ((size_t)nt * 2 + ks) * 512 + lane * 8;
            short8 B1 = *(const short8*)(bp + base);
            short8 B2 = *(const short8*)(bp + PB + base);
            short8 B3 = *(const short8*)(bp + 2 * PB + base);
            acc[t] = MFMA16(A1[ks], B1, acc[t]);
            acc[t] = MFMA16(A1[ks], B2, acc[t]);
            acc[t] = MFMA16(A2[ks], B1, acc[t]);
            acc[t] = MFMA16(A2[ks], B2, acc[t]);
            acc[t] = MFMA16(A1[ks], B3, acc[t]);
            acc[t] = MFMA16(A3[ks], B1, acc[t]);
        }
    }

    float inv_[16], bon_[16];
    #pragma unroll
    for (int t = 0; t < 16; ++t) {
        inv_[t] = invn_g[n0 + t * 16 + r_];
        bon_[t] = bonus_g[n0 + t * 16 + r_];
    }

    // pass 1: per row r -> wave-local (max, expsum) -> LDS
    float m_[4], s_[4];
    #pragma unroll
    for (int r = 0; r < 4; ++r) {
        float m = -INFINITY;
        #pragma unroll
        for (int t = 0; t < 16; ++t)
            m = fmaxf(m, fmaf(acc[t][r], inv_[t], bon_[t]));
        #pragma unroll
        for (int d = 1; d <= 8; d <<= 1)
            m = fmaxf(m, __shfl_xor(m, d));
        float s = 0.f;
        #pragma unroll
        for (int t = 0; t < 16; ++t)
            s += __expf(fmaf(acc[t][r], inv_[t], bon_[t]) - m);
        #pragma unroll
        for (int d = 1; d <= 8; d <<= 1)
            s += __shfl_xor(s, d);
        m_[r] = m; s_[r] = s;
        if (r_ == 0) red[g_ * 4 + r][wave] = make_float2(m, s);
    }
    __syncthreads();

    // pass 2: cross-wave combine, recompute P, weighted pool
    const unsigned PTAB = 0xF5634F01u;
    const int pn = (PTAB >> (wave * 4)) & 0xF;
    float accw[16];
    #pragma unroll
    for (int t = 0; t < 16; ++t) accw[t] = 0.f;

    #pragma unroll
    for (int r = 0; r < 4; ++r) {
        const int row = g_ * 4 + r;
        float m = m_[r], s = s_[r];
        float M = m, Z = s;
        if (pn != 0xF) {
            float2 q = red[row][pn];
            M = fmaxf(m, q.x);
            Z = s * __expf(m - M) + q.y * __expf(q.x - M);
        }
        float coef = imp[rowBase + row] / Z * __expf(m - M);
        #pragma unroll
        for (int t = 0; t < 16; ++t)
            accw[t] = fmaf(coef, __expf(fmaf(acc[t][r], inv_[t], bon_[t]) - m), accw[t]);
    }

    // reduce the 4 g-groups (rows) per column, then write
    #pragma unroll
    for (int t = 0; t < 16; ++t) {
        accw[t] += __shfl_xor(accw[t], 16);
        accw[t] += __shfl_xor(accw[t], 32);
    }
    #pragma unroll
    for (int tt = 0; tt < 4; ++tt) {
        int t = g_ * 4 + tt;
        float v = (tt == 0) ? accw[g_ * 4] : (tt == 1) ? accw[g_ * 4 + 1]
                : (tt == 2) ? accw[g_ * 4 + 2] : accw[g_ * 4 + 3];
        atomicAdd(&wout[b * 2048 + n0 + t * 16 + r_], v);
    }
}

// ---------------- top-k + softmax + sorted indices, one wave per (b,route) --
__global__ void topk_kernel(const float* __restrict__ w, float* __restrict__ out)
{
    const int lane = threadIdx.x;
    const int blk = blockIdx.x;          // 0..39
    const int b = blk / 5;
    const int route = blk % 5;

    const int segoff[5] = {0, 512, 768, 1280, 1792};
    const int seglen[5] = {512, 256, 512, 512, 256};
    const int kk[5]     = {64, 32, 64, 64, 32};
    const int soff[5]   = {0, 64, 96, 160, 224};
    const int ibase[5]  = {2048, 2560, 2816, 3328, 3840};

    const int L = seglen[route];
    const int K = kk[route];
    const int nv = L >> 6;               // 4 or 8 values per lane

    float v[8];
    #pragma unroll
    for (int i = 0; i < 8; ++i) {
        v[i] = -INFINITY;
        if (i < nv) v[i] = w[b * 2048 + segoff[route] + lane + 64 * i];
    }

    float selv = 0.f; int seli = 0;
    for (int it = 0; it < K; ++it) {
        float bv = -INFINITY; int bi = 0x7fffffff;
        #pragma unroll
        for (int i = 0; i < 8; ++i) {
            int li = lane + 64 * i;
            if (v[i] > bv || (v[i] == bv && li < bi)) { bv = v[i]; bi = li; }
        }
        for (int d = 1; d < 64; d <<= 1) {
            float ov = __shfl_xor(bv, d);
            int   oi = __shfl_xor(bi, d);
            if (ov > bv || (ov == bv && oi < bi)) { bv = ov; bi = oi; }
        }
        if (lane == it) { selv = bv; seli = bi; }
        #pragma unroll
        for (int i = 0; i < 8; ++i)
            if ((bi >> 6) == i && (bi & 63) == lane) v[i] = -INFINITY;
    }

    float m = __shfl(selv, 0);
    float e = (lane < K) ? __expf(selv - m) : 0.f;
    float s = e;
    for (int d = 1; d < 64; d <<= 1) s += __shfl_xor(s, d);
    if (lane < K) out[b * 256 + soff[route] + lane] = e / s;

    int rank = 0;
    for (int j = 0; j < K; ++j) {
        int oj = __shfl(seli, j);
        if (oj < seli) rank++;
    }
    if (lane < K) out[ibase[route] + b * K + rank] = (float)seli;
}

extern "C" void kernel_launch(void* const* d_in, const int* in_sizes, int n_in,
                              void* d_out, int out_size, void* d_ws, size_t ws_size,
                              hipStream_t stream)
{
    const float* x        = (const float*)d_in[0];
    const float* imp      = (const float*)d_in[1];
    const float* proj_w   = (const float*)d_in[2];
    const float* proj_b   = (const float*)d_in[3];
    const float* emb      = (const float*)d_in[4];
    const float* emb_rel  = (const float*)d_in[5];
    const float* ema_qk   = (const float*)d_in[6];
    const float* ema_v    = (const float*)d_in[7];
    const float* ema_rel  = (const float*)d_in[8];
    const float* ema_val  = (const float*)d_in[9];
    float* out = (float*)d_out;

    float* invn  = (float*)d_ws;                       // 2048 f32
    float* bonus = invn + 2048;                        // 2048 f32
    float* wacc  = bonus + 2048;                       // 16384 f32
    unsigned short* wp = (unsigned short*)(wacc + 16384);  // 3*PB u16
    unsigned short* bp = wp + 3 * PB;                  // 3*PB u16
    unsigned short* hs = bp + 3 * PB;                  // 3*PH u16 (6 MB)

    prep_kernel<<<32, 64, 0, stream>>>(emb, emb_rel, ema_qk, ema_v, ema_rel, ema_val, invn, bonus, wacc);
    wtpack3_kernel<<<64, 256, 0, stream>>>(proj_w, wp);
    embpack_kernel<<<64, 256, 0, stream>>>(emb, emb_rel, bp);
    proj_kernel<<<512, 256, 0, stream>>>(x, wp, proj_b, hs);
    route_kernel<<<1024, 512, 0, stream>>>(hs, bp, imp, invn, bonus, wacc);
    topk_kernel<<<40, 64, 0, stream>>>(wacc, out);
}